// Round 1
// baseline (1300.355 us; speedup 1.0000x reference)
//
#include <hip/hip_runtime.h>

typedef unsigned short u16;
typedef unsigned int   u32;
typedef __bf16  bf16x8 __attribute__((ext_vector_type(8)));
typedef float   f32x4  __attribute__((ext_vector_type(4)));

#define DEV __device__ __forceinline__

// ---------- scalar bf16 helpers (bit-level, RNE) ----------
DEV float bf2f(u16 b) { return __uint_as_float(((u32)b) << 16); }
DEV u16 f2bf(float f) {
  u32 u = __float_as_uint(f);
  u32 r = (u + 0x7fffu + ((u >> 16) & 1u)) >> 16;
  return (u16)r;
}

// ---------- async global->LDS, 16B per lane, dest = wave-uniform base + lane*16 ----------
DEV void gll16(const void* g, void* l) {
  __builtin_amdgcn_global_load_lds((const __attribute__((address_space(1))) void*)g,
                                   (__attribute__((address_space(3))) void*)l, 16, 0, 0);
}

// ===========================================================================
// LayerNorm: x fp32 [4096][2048] -> xn bf16. One block per row.
// ===========================================================================
__global__ __launch_bounds__(256) void ln_kernel(const float* __restrict__ x,
                                                 const float* __restrict__ gamma,
                                                 u16* __restrict__ xn) {
  __shared__ float red[4];
  const int row = blockIdx.x, t = threadIdx.x;
  const float* xr = x + (long)row * 2048;
  float4 v0 = ((const float4*)xr)[t * 2];
  float4 v1 = ((const float4*)xr)[t * 2 + 1];
  float s = (v0.x + v0.y) + (v0.z + v0.w) + (v1.x + v1.y) + (v1.z + v1.w);
#pragma unroll
  for (int o = 32; o >= 1; o >>= 1) s += __shfl_xor(s, o, 64);
  if ((t & 63) == 0) red[t >> 6] = s;
  __syncthreads();
  const float mu = (red[0] + red[1] + red[2] + red[3]) * (1.f / 2048.f);
  __syncthreads();
  float a0 = v0.x - mu, a1 = v0.y - mu, a2 = v0.z - mu, a3 = v0.w - mu;
  float a4 = v1.x - mu, a5 = v1.y - mu, a6 = v1.z - mu, a7 = v1.w - mu;
  float q = a0*a0 + a1*a1 + a2*a2 + a3*a3 + a4*a4 + a5*a5 + a6*a6 + a7*a7;
#pragma unroll
  for (int o = 32; o >= 1; o >>= 1) q += __shfl_xor(q, o, 64);
  if ((t & 63) == 0) red[t >> 6] = q;
  __syncthreads();
  const float var = (red[0] + red[1] + red[2] + red[3]) * (1.f / 2048.f);
  const float rs = rsqrtf(var + 1e-5f);
  float4 g0 = ((const float4*)gamma)[t * 2];
  float4 g1 = ((const float4*)gamma)[t * 2 + 1];
  union { uint4 u; u16 h[8]; } o;
  o.h[0] = f2bf(a0 * rs * g0.x); o.h[1] = f2bf(a1 * rs * g0.y);
  o.h[2] = f2bf(a2 * rs * g0.z); o.h[3] = f2bf(a3 * rs * g0.w);
  o.h[4] = f2bf(a4 * rs * g1.x); o.h[5] = f2bf(a5 * rs * g1.y);
  o.h[6] = f2bf(a6 * rs * g1.z); o.h[7] = f2bf(a7 * rs * g1.w);
  ((uint4*)(xn + (long)row * 2048))[t] = o.u;
}

// ===========================================================================
// LoRA rank-8 outer products: dst[k][doff+n] = sum_r A[k][r]*B[r][n]
// ===========================================================================
__global__ __launch_bounds__(256) void lora_mm(const float* __restrict__ A,
                                               const float* __restrict__ B,
                                               float* __restrict__ dst,
                                               int ncols, int dstride, int doff) {
  int n = blockIdx.x * 256 + threadIdx.x;
  int k = blockIdx.y;
  if (n >= ncols) return;
  float acc = 0.f;
#pragma unroll
  for (int r = 0; r < 8; r++) acc += A[k * 8 + r] * B[r * ncols + n];
  dst[(long)k * dstride + doff + n] = acc;
}

// ===========================================================================
// Transpose + (optional) delta add + convert fp32 -> bf16.
// src [rows][cols] (stride sstride); dst[n][dst_off + k], stride dst_stride.
// ===========================================================================
__global__ __launch_bounds__(256) void transpose_conv(const float* __restrict__ src, int sstride,
                                                      const float* __restrict__ delta, int dstride, int dcols,
                                                      u16* __restrict__ dst, int dst_stride, int dst_off) {
  __shared__ float tile[32][33];
  const int c0 = blockIdx.x * 32, r0 = blockIdx.y * 32;
  const int tx = threadIdx.x & 31, ty = threadIdx.x >> 5;
  const bool hasd = (delta != nullptr) && (c0 < dcols);
#pragma unroll
  for (int i = 0; i < 4; i++) {
    int r = r0 + ty + i * 8;
    float v = src[(long)r * sstride + c0 + tx];
    if (hasd) v += delta[(long)r * dstride + c0 + tx];
    tile[ty + i * 8][tx] = v;
  }
  __syncthreads();
#pragma unroll
  for (int i = 0; i < 4; i++) {
    int n = c0 + ty + i * 8;
    dst[(long)n * dst_stride + dst_off + r0 + tx] = f2bf(tile[tx][ty + i * 8]);
  }
}

// ===========================================================================
// bf16 GEMM, m97 structure: C[M][N] = A[M][K] @ Bt[N][K]^T
// 128x128 tile, 4 waves (2x2), BK=32, global_load_lds staging, 16x16x32 MFMA.
// OUT_BF16: 1 -> bf16 C, 0 -> fp32 C.
// ===========================================================================
template <int OUT_BF16>
__global__ __launch_bounds__(256, 2) void gemm_bt(const u16* __restrict__ A,
                                                  const u16* __restrict__ Bt,
                                                  void* __restrict__ Cv,
                                                  int K, int lda, int ldc) {
  __shared__ u16 As[128 * 32];
  __shared__ u16 Bs[128 * 32];
  const int bn0 = blockIdx.x * 128, bm0 = blockIdx.y * 128;
  const int tid = threadIdx.x, wave = tid >> 6, lane = tid & 63;
  const int wm = wave >> 1, wn = wave & 1;
  const int frow = lane & 15, fk = (lane >> 4) * 8;
  // staging: granule g (16B = 8 elems) -> row g>>2, colgrp g&3
  const int gr = wave * 64 + lane;
  const int ar = gr >> 2, ac = (gr & 3) * 8;
  const u16* Ap0 = A + (long)(bm0 + ar) * lda + ac;
  const u16* Ap1 = A + (long)(bm0 + ar + 64) * lda + ac;
  const u16* Bp0 = Bt + (long)(bn0 + ar) * K + ac;
  const u16* Bp1 = Bt + (long)(bn0 + ar + 64) * K + ac;
  u16* As0 = &As[wave * 512]; u16* As1 = &As[2048 + wave * 512];
  u16* Bs0 = &Bs[wave * 512]; u16* Bs1 = &Bs[2048 + wave * 512];

  const f32x4 z4 = {0.f, 0.f, 0.f, 0.f};
  f32x4 acc[4][4];
#pragma unroll
  for (int m = 0; m < 4; m++)
#pragma unroll
    for (int n = 0; n < 4; n++) acc[m][n] = z4;

  for (int k0 = 0; k0 < K; k0 += 32) {
    __syncthreads();
    gll16(Ap0 + k0, As0);
    gll16(Ap1 + k0, As1);
    gll16(Bp0 + k0, Bs0);
    gll16(Bp1 + k0, Bs1);
    __syncthreads();
    bf16x8 a[4], b[4];
#pragma unroll
    for (int m = 0; m < 4; m++) a[m] = *(const bf16x8*)&As[(wm * 64 + m * 16 + frow) * 32 + fk];
#pragma unroll
    for (int n = 0; n < 4; n++) b[n] = *(const bf16x8*)&Bs[(wn * 64 + n * 16 + frow) * 32 + fk];
#pragma unroll
    for (int m = 0; m < 4; m++)
#pragma unroll
      for (int n = 0; n < 4; n++)
        acc[m][n] = __builtin_amdgcn_mfma_f32_16x16x32_bf16(a[m], b[n], acc[m][n], 0, 0, 0);
  }
  // epilogue: C row = (lane>>4)*4 + r, col = lane&15
#pragma unroll
  for (int m = 0; m < 4; m++) {
    int row0 = bm0 + wm * 64 + m * 16 + (lane >> 4) * 4;
#pragma unroll
    for (int n = 0; n < 4; n++) {
      int col = bn0 + wn * 64 + n * 16 + frow;
#pragma unroll
      for (int r = 0; r < 4; r++) {
        if (OUT_BF16) ((u16*)Cv)[(long)(row0 + r) * ldc + col] = f2bf(acc[m][n][r]);
        else          ((float*)Cv)[(long)(row0 + r) * ldc + col] = acc[m][n][r];
      }
    }
  }
}

// ===========================================================================
// Rope q (cols 0..2047, scaled by dh^-0.5) and k (cols 2048..2175) in place;
// also scatter v (cols 2176..2303) into vt[b][d][pos].
// ===========================================================================
__global__ __launch_bounds__(256) void rope_kernel(u16* __restrict__ fused, u16* __restrict__ vt) {
  const int row = blockIdx.x;
  const int b = row >> 11, pos = row & 2047;
  u16* fr = fused + (long)row * 18688;
  const int t = threadIdx.x;
  const float fpos = (float)pos;
  const float QS = 0.08838834764831845f;  // 128^-0.5
#pragma unroll
  for (int i = 0; i < 4; i++) {
    int p = t + i * 256;          // 0..1023: 16 heads x 64 pairs
    int hh = p >> 6, d = p & 63;
    float ang = fpos * expf((float)d * -0.14391157f);  // ln(10000)/64
    float sn, cs; sincosf(ang, &sn, &cs);
    int base = hh * 128 + d;
    float x1 = bf2f(fr[base]), x2 = bf2f(fr[base + 64]);
    fr[base]      = f2bf((x1 * cs - x2 * sn) * QS);
    fr[base + 64] = f2bf((x2 * cs + x1 * sn) * QS);
  }
  if (t < 64) {
    int d = t;
    float ang = fpos * expf((float)d * -0.14391157f);
    float sn, cs; sincosf(ang, &sn, &cs);
    float x1 = bf2f(fr[2048 + d]), x2 = bf2f(fr[2112 + d]);
    fr[2048 + d] = f2bf(x1 * cs - x2 * sn);
    fr[2112 + d] = f2bf(x2 * cs + x1 * sn);
  }
  if (t < 128) vt[((long)(b * 128 + t)) * 2048 + pos] = fr[2176 + t];
}

// ===========================================================================
// Causal MQA flash attention. Block = (qt, h, b), 128 q-rows, 4 waves x 32 rows.
// K tile and V^T tile staged via global_load_lds; P repacked through K's LDS.
// ===========================================================================
__global__ __launch_bounds__(256, 2) void attn_kernel(const u16* __restrict__ fused,
                                                      const u16* __restrict__ vt,
                                                      u16* __restrict__ act2) {
  __shared__ u16 Ks[128 * 128];   // [kv][d]  (also reused as P staging)
  __shared__ u16 Vts[128 * 128];  // [d][kv]
  const int qt = blockIdx.x, h = blockIdx.y, b = blockIdx.z;
  const int tid = threadIdx.x, wave = tid >> 6, lane = tid & 63;
  const int frow = lane & 15, fk4 = lane >> 4;
  const long qrow0 = (long)b * 2048 + qt * 128;

  // Q fragments (A-operand): row = lane&15, k = (lane>>4)*8
  bf16x8 qf[2][4];
#pragma unroll
  for (int m = 0; m < 2; m++)
#pragma unroll
    for (int kk = 0; kk < 4; kk++)
      qf[m][kk] = *(const bf16x8*)&fused[(qrow0 + wave * 32 + m * 16 + frow) * 18688 +
                                         h * 128 + kk * 32 + fk4 * 8];

  const f32x4 z4 = {0.f, 0.f, 0.f, 0.f};
  f32x4 Oacc[2][8];
#pragma unroll
  for (int m = 0; m < 2; m++)
#pragma unroll
    for (int d = 0; d < 8; d++) Oacc[m][d] = z4;
  float mrun[2][4], lrun[2][4];
#pragma unroll
  for (int m = 0; m < 2; m++)
#pragma unroll
    for (int r = 0; r < 4; r++) { mrun[m][r] = -1e30f; lrun[m][r] = 0.f; }

  for (int jt = 0; jt <= qt; ++jt) {
    __syncthreads();  // previous iteration fully done with LDS
    const long kb = (long)b * 2048 + jt * 128;
#pragma unroll
    for (int s8 = 0; s8 < 8; s8++) {
      int gb = (s8 * 4 + wave) * 64;
      int g = gb + lane;
      int kv = g >> 4, gc8 = (g & 15) * 8;
      gll16(&fused[(kb + kv) * 18688 + 2048 + gc8], &Ks[gb * 8]);
      gll16(&vt[((long)b * 128 + kv) * 2048 + jt * 128 + gc8], &Vts[gb * 8]);
    }
    __syncthreads();

    // S = Q @ K^T
    f32x4 sc[2][8];
#pragma unroll
    for (int m = 0; m < 2; m++)
#pragma unroll
      for (int n = 0; n < 8; n++) sc[m][n] = z4;
#pragma unroll
    for (int n = 0; n < 8; n++) {
#pragma unroll
      for (int kk = 0; kk < 4; kk++) {
        bf16x8 kf = *(const bf16x8*)&Ks[(n * 16 + frow) * 128 + kk * 32 + fk4 * 8];
        sc[0][n] = __builtin_amdgcn_mfma_f32_16x16x32_bf16(qf[0][kk], kf, sc[0][n], 0, 0, 0);
        sc[1][n] = __builtin_amdgcn_mfma_f32_16x16x32_bf16(qf[1][kk], kf, sc[1][n], 0, 0, 0);
      }
    }
    if (jt == qt) {  // causal mask on diagonal tile
#pragma unroll
      for (int m = 0; m < 2; m++)
#pragma unroll
        for (int n = 0; n < 8; n++)
#pragma unroll
          for (int r = 0; r < 4; r++) {
            int qp = wave * 32 + m * 16 + fk4 * 4 + r;
            int kp = n * 16 + frow;
            if (kp > qp) sc[m][n][r] = -1e30f;
          }
    }
    // online softmax (rows live across lane&15 groups)
#pragma unroll
    for (int m = 0; m < 2; m++) {
#pragma unroll
      for (int r = 0; r < 4; r++) {
        float mx = -1e30f;
#pragma unroll
        for (int n = 0; n < 8; n++) mx = fmaxf(mx, sc[m][n][r]);
#pragma unroll
        for (int o = 1; o < 16; o <<= 1) mx = fmaxf(mx, __shfl_xor(mx, o, 64));
        float mnew = fmaxf(mrun[m][r], mx);
        float corr = __expf(mrun[m][r] - mnew);
        mrun[m][r] = mnew;
        float rsum = 0.f;
#pragma unroll
        for (int n = 0; n < 8; n++) {
          float p = __expf(sc[m][n][r] - mnew);
          sc[m][n][r] = p;
          rsum += p;
        }
#pragma unroll
        for (int o = 1; o < 16; o <<= 1) rsum += __shfl_xor(rsum, o, 64);
        lrun[m][r] = lrun[m][r] * corr + rsum;
#pragma unroll
        for (int d = 0; d < 8; d++) Oacc[m][d][r] *= corr;
      }
    }
    __syncthreads();  // all waves done reading Ks -> reuse as P staging
    u16* Pw = &Ks[wave * 4096];  // 32 rows x 128 kv per wave
#pragma unroll
    for (int m = 0; m < 2; m++)
#pragma unroll
      for (int n = 0; n < 8; n++)
#pragma unroll
        for (int r = 0; r < 4; r++)
          Pw[(m * 16 + fk4 * 4 + r) * 128 + n * 16 + frow] = f2bf(sc[m][n][r]);
    // PV: A = P (rows=q), B^T = V^T[d][kv]
#pragma unroll
    for (int kk = 0; kk < 4; kk++) {
      bf16x8 p0 = *(const bf16x8*)&Pw[(frow) * 128 + kk * 32 + fk4 * 8];
      bf16x8 p1 = *(const bf16x8*)&Pw[(16 + frow) * 128 + kk * 32 + fk4 * 8];
#pragma unroll
      for (int d = 0; d < 8; d++) {
        bf16x8 vf = *(const bf16x8*)&Vts[(d * 16 + frow) * 128 + kk * 32 + fk4 * 8];
        Oacc[0][d] = __builtin_amdgcn_mfma_f32_16x16x32_bf16(p0, vf, Oacc[0][d], 0, 0, 0);
        Oacc[1][d] = __builtin_amdgcn_mfma_f32_16x16x32_bf16(p1, vf, Oacc[1][d], 0, 0, 0);
      }
    }
  }
  // normalize + store to act2 cols [0,2048)
#pragma unroll
  for (int m = 0; m < 2; m++)
#pragma unroll
    for (int d = 0; d < 8; d++)
#pragma unroll
      for (int r = 0; r < 4; r++) {
        long row = qrow0 + wave * 32 + m * 16 + fk4 * 4 + r;
        act2[row * 10240 + h * 128 + d * 16 + frow] = f2bf(Oacc[m][d][r] / lrun[m][r]);
      }
}

// ===========================================================================
// SwiGLU: act2[:, 2048+j] = silu(fused[:,10496+j]) * fused[:,2304+j]
// ===========================================================================
__global__ __launch_bounds__(256) void swiglu_kernel(const u16* __restrict__ fused,
                                                     u16* __restrict__ act2) {
  long idx8 = ((long)blockIdx.x * 256 + threadIdx.x) * 8;
  int row = (int)(idx8 >> 13);
  int j = (int)(idx8 & 8191);
  const u16* fr = fused + (long)row * 18688;
  union { uint4 u; u16 h[8]; } xv, gv, ov;
  xv.u = *(const uint4*)&fr[2304 + j];
  gv.u = *(const uint4*)&fr[10496 + j];
#pragma unroll
  for (int i = 0; i < 8; i++) {
    float xf = bf2f(xv.h[i]);
    float gf = bf2f(gv.h[i]);
    float sg = gf / (1.f + __expf(-gf));
    ov.h[i] = f2bf(sg * xf);
  }
  *(uint4*)&act2[(long)row * 10240 + 2048 + j] = ov.u;
}

// ===========================================================================
extern "C" void kernel_launch(void* const* d_in, const int* in_sizes, int n_in,
                              void* d_out, int out_size, void* d_ws, size_t ws_size,
                              hipStream_t stream) {
  (void)in_sizes; (void)n_in; (void)out_size; (void)ws_size;
  const float* x          = (const float*)d_in[0];
  const float* gamma      = (const float*)d_in[1];
  const float* w_fused    = (const float*)d_in[2];
  const float* w_attn_out = (const float*)d_in[3];
  const float* w_ff_out   = (const float*)d_in[4];
  const float* qA = (const float*)d_in[5];
  const float* qB = (const float*)d_in[6];
  const float* kA = (const float*)d_in[7];
  const float* kB = (const float*)d_in[8];
  const float* vA = (const float*)d_in[9];
  const float* vB = (const float*)d_in[10];
  const float* oA = (const float*)d_in[11];
  const float* oB = (const float*)d_in[12];
  float* out = (float*)d_out;

  // workspace layout (requires ~374 MiB)
  char* w = (char*)d_ws;
  auto alloc = [&](size_t bytes) { char* p = w; w += (bytes + 255) & ~(size_t)255; return p; };
  u16*   xn     = (u16*)alloc((size_t)4096 * 2048 * 2);
  u16*   wf_t   = (u16*)alloc((size_t)18688 * 2048 * 2);   // [n=18688][k=2048]
  u16*   wcat_t = (u16*)alloc((size_t)2048 * 10240 * 2);   // [n=2048][k=10240]
  u16*   fused  = (u16*)alloc((size_t)4096 * 18688 * 2);   // [row][18688]
  u16*   act2   = (u16*)alloc((size_t)4096 * 10240 * 2);   // [row][attn(2048)|ff(8192)]
  u16*   vtb    = (u16*)alloc((size_t)2 * 128 * 2048 * 2); // [b][d][pos]
  float* delta  = (float*)alloc((size_t)2048 * 2304 * 4);  // LoRA deltas

  // 1) LayerNorm
  ln_kernel<<<4096, 256, 0, stream>>>(x, gamma, xn);

  // 2) LoRA deltas for q/k/v, fold+transpose w_fused -> wf_t (bf16)
  lora_mm<<<dim3(8, 2048), 256, 0, stream>>>(qA, qB, delta, 2048, 2304, 0);
  lora_mm<<<dim3(1, 2048), 256, 0, stream>>>(kA, kB, delta, 128, 2304, 2048);
  lora_mm<<<dim3(1, 2048), 256, 0, stream>>>(vA, vB, delta, 128, 2304, 2176);
  transpose_conv<<<dim3(584, 64), 256, 0, stream>>>(w_fused, 18688, delta, 2304, 2304,
                                                    wf_t, 2048, 0);

  // 3) fused GEMM: xn @ wf' -> fused (bf16)
  gemm_bt<1><<<dim3(146, 32), 256, 0, stream>>>(xn, wf_t, fused, 2048, 2048, 18688);

  // 4) rope q/k in place + build V^T
  rope_kernel<<<4096, 256, 0, stream>>>(fused, vtb);

  // 5) output weights: w_attn_out + oA@oB, w_ff_out -> wcat_t (transposed bf16)
  lora_mm<<<dim3(8, 2048), 256, 0, stream>>>(oA, oB, delta, 2048, 2048, 0);
  transpose_conv<<<dim3(64, 64), 256, 0, stream>>>(w_attn_out, 2048, delta, 2048, 2048,
                                                   wcat_t, 10240, 0);
  transpose_conv<<<dim3(64, 256), 256, 0, stream>>>(w_ff_out, 2048, (const float*)nullptr, 0, 0,
                                                    wcat_t, 10240, 2048);

  // 6) flash attention -> act2[:, 0:2048]
  attn_kernel<<<dim3(16, 16, 2), 256, 0, stream>>>(fused, vtb, act2);

  // 7) SwiGLU -> act2[:, 2048:10240]
  swiglu_kernel<<<16384, 256, 0, stream>>>(fused, act2);

  // 8) concat GEMM: [attn_out | ff] @ [[w_attn_out'],[w_ff_out]] -> d_out (fp32)
  gemm_bt<0><<<dim3(16, 32), 256, 0, stream>>>(act2, wcat_t, out, 10240, 10240, 2048);
}

// Round 4
// 1077.076 us; speedup vs baseline: 1.2073x; 1.2073x over previous
//
#include <hip/hip_runtime.h>

typedef unsigned short u16;
typedef unsigned int   u32;
typedef __bf16  bf16x8 __attribute__((ext_vector_type(8)));
typedef float   f32x4  __attribute__((ext_vector_type(4)));

#define DEV __device__ __forceinline__

// ---------- scalar bf16 helpers (bit-level, RNE) ----------
DEV float bf2f(u16 b) { return __uint_as_float(((u32)b) << 16); }
DEV u16 f2bf(float f) {
  u32 u = __float_as_uint(f);
  u32 r = (u + 0x7fffu + ((u >> 16) & 1u)) >> 16;
  return (u16)r;
}

// ---------- async global->LDS, 16B per lane, dest = wave-uniform base + lane*16 ----------
DEV void gll16(const void* g, void* l) {
  __builtin_amdgcn_global_load_lds((const __attribute__((address_space(1))) void*)g,
                                   (__attribute__((address_space(3))) void*)l, 16, 0, 0);
}
DEV void sb0() { __builtin_amdgcn_sched_barrier(0); }
DEV void wg_barrier() { sb0(); __builtin_amdgcn_s_barrier(); sb0(); }
template <int N> DEV void vm_wait() {
  if constexpr (N == 6)      asm volatile("s_waitcnt vmcnt(6)" ::: "memory");
  else if constexpr (N == 4) asm volatile("s_waitcnt vmcnt(4)" ::: "memory");
  else                       asm volatile("s_waitcnt vmcnt(0)" ::: "memory");
}

// ===========================================================================
// LayerNorm: x fp32 [4096][2048] -> xn bf16. One block per row.
// ===========================================================================
__global__ __launch_bounds__(256) void ln_kernel(const float* __restrict__ x,
                                                 const float* __restrict__ gamma,
                                                 u16* __restrict__ xn) {
  __shared__ float red[4];
  const int row = blockIdx.x, t = threadIdx.x;
  const float* xr = x + (long)row * 2048;
  float4 v0 = ((const float4*)xr)[t * 2];
  float4 v1 = ((const float4*)xr)[t * 2 + 1];
  float s = (v0.x + v0.y) + (v0.z + v0.w) + (v1.x + v1.y) + (v1.z + v1.w);
#pragma unroll
  for (int o = 32; o >= 1; o >>= 1) s += __shfl_xor(s, o, 64);
  if ((t & 63) == 0) red[t >> 6] = s;
  __syncthreads();
  const float mu = (red[0] + red[1] + red[2] + red[3]) * (1.f / 2048.f);
  __syncthreads();
  float a0 = v0.x - mu, a1 = v0.y - mu, a2 = v0.z - mu, a3 = v0.w - mu;
  float a4 = v1.x - mu, a5 = v1.y - mu, a6 = v1.z - mu, a7 = v1.w - mu;
  float q = a0*a0 + a1*a1 + a2*a2 + a3*a3 + a4*a4 + a5*a5 + a6*a6 + a7*a7;
#pragma unroll
  for (int o = 32; o >= 1; o >>= 1) q += __shfl_xor(q, o, 64);
  if ((t & 63) == 0) red[t >> 6] = q;
  __syncthreads();
  const float var = (red[0] + red[1] + red[2] + red[3]) * (1.f / 2048.f);
  const float rs = rsqrtf(var + 1e-5f);
  float4 g0 = ((const float4*)gamma)[t * 2];
  float4 g1 = ((const float4*)gamma)[t * 2 + 1];
  union { uint4 u; u16 h[8]; } o;
  o.h[0] = f2bf(a0 * rs * g0.x); o.h[1] = f2bf(a1 * rs * g0.y);
  o.h[2] = f2bf(a2 * rs * g0.z); o.h[3] = f2bf(a3 * rs * g0.w);
  o.h[4] = f2bf(a4 * rs * g1.x); o.h[5] = f2bf(a5 * rs * g1.y);
  o.h[6] = f2bf(a6 * rs * g1.z); o.h[7] = f2bf(a7 * rs * g1.w);
  ((uint4*)(xn + (long)row * 2048))[t] = o.u;
}

// ===========================================================================
// LoRA rank-8 outer products: dst[k][doff+n] = sum_r A[k][r]*B[r][n]
// ===========================================================================
__global__ __launch_bounds__(256) void lora_mm(const float* __restrict__ A,
                                               const float* __restrict__ B,
                                               float* __restrict__ dst,
                                               int ncols, int dstride, int doff) {
  int n = blockIdx.x * 256 + threadIdx.x;
  int k = blockIdx.y;
  if (n >= ncols) return;
  float acc = 0.f;
#pragma unroll
  for (int r = 0; r < 8; r++) acc += A[k * 8 + r] * B[r * ncols + n];
  dst[(long)k * dstride + doff + n] = acc;
}

// ===========================================================================
// Transpose + (optional) delta add + convert fp32 -> bf16.
// ===========================================================================
__global__ __launch_bounds__(256) void transpose_conv(const float* __restrict__ src, int sstride,
                                                      const float* __restrict__ delta, int dstride, int dcols,
                                                      u16* __restrict__ dst, int dst_stride, int dst_off) {
  __shared__ float tile[32][33];
  const int c0 = blockIdx.x * 32, r0 = blockIdx.y * 32;
  const int tx = threadIdx.x & 31, ty = threadIdx.x >> 5;
  const bool hasd = (delta != nullptr) && (c0 < dcols);
#pragma unroll
  for (int i = 0; i < 4; i++) {
    int r = r0 + ty + i * 8;
    float v = src[(long)r * sstride + c0 + tx];
    if (hasd) v += delta[(long)r * dstride + c0 + tx];
    tile[ty + i * 8][tx] = v;
  }
  __syncthreads();
#pragma unroll
  for (int i = 0; i < 4; i++) {
    int n = c0 + ty + i * 8;
    dst[(long)n * dst_stride + dst_off + r0 + tx] = f2bf(tile[tx][ty + i * 8]);
  }
}

// ===========================================================================
// 8-phase 256xBN bf16 GEMM (T1+T2+T3+T4+T5): C[M][N] = A[M][K] @ Bt[N][K]^T
// 8 waves (2Mx4N), BK=64, double-buffered LDS, XOR-swizzled (both sides),
// counted vmcnt (never 0 in steady state), setprio around MFMA clusters.
// BN=256: LDS 128KB, vmcnt(6).  BN=128: LDS 96KB, vmcnt(4).
// Schedule (issue slots per tile t): ph0: A1(t+1) | ph2: B0(t+2) | ph3: A0(t+2), B1(t+2)
// Safety: every LDS region's last ds_read is barrier-certified >=1 phase
// before its overwriting global_load_lds is issued.
// ===========================================================================
template <int OUT_BF16, int BN>
__global__ __launch_bounds__(512, 1) void gemm8p(const u16* __restrict__ A,
                                                 const u16* __restrict__ Bt,
                                                 void* __restrict__ Cv,
                                                 int K, int lda, int ldb, int ldc, int ntm) {
  extern __shared__ char lds[];
  constexpr int LB   = (BN == 256) ? 2 : 1;   // gll16 rounds per B half-tile
  constexpr int NF   = BN / 64;               // n-frags per wave (4 or 2)
  constexpr int NQ   = NF / 2;                // n-frags per quadrant (2 or 1)
  constexpr int ABUF = 256 * 64 * 2;          // 32 KiB per A buffer
  constexpr int BBUF = BN * 64 * 2;
  constexpr int VMN  = 2 + 2 * LB;            // counted vmcnt at tile boundary

  const int tid = threadIdx.x, wave = tid >> 6, lane = tid & 63;
  const int wm = wave >> 2, wn = wave & 3;
  const int frow = lane & 15, fks = lane >> 4;

  // T1: XCD-aware bijective swizzle (gridDim.x % 8 == 0 for both call sites)
  const int nwg = gridDim.x, orig = blockIdx.x;
  const int swz = (orig & 7) * (nwg >> 3) + (orig >> 3);
  const int tm = swz % ntm, tn = swz / ntm;
  const long bm0 = (long)tm * 256, bn0 = (long)tn * BN;

  char* Ab = lds;
  char* Bb = lds + 2 * ABUF;
  const int NT = K >> 6;

  // staging geometry: granule G = r*512 + wave*64 + lane; LDS byte = G*16 (linear);
  // global col granule = (G&7) ^ ((G>>3)&7)  (inverse swizzle on SOURCE)
  const int G0 = wave * 64 + lane;
  const int r0g = G0 >> 3, c0g = ((G0 & 7) ^ (r0g & 7)) * 8;
  const int G1 = 512 + G0;
  const int r1g = G1 >> 3, c1g = ((G1 & 7) ^ (r1g & 7)) * 8;

  auto stageA = [&](int kt, int X) {
    char* base = Ab + (kt & 1) * ABUF + X * 16384 + wave * 1024;
    const u16* g = A + (bm0 + X * 128) * lda + kt * 64;
    gll16(g + (long)r0g * lda + c0g, base);
    gll16(g + (long)r1g * lda + c1g, base + 8192);
  };
  auto stageB = [&](int kt, int X) {
    char* base = Bb + (kt & 1) * BBUF + X * (BBUF / 2) + wave * 1024;
    const u16* g = Bt + (bn0 + X * (BN / 2)) * ldb + kt * 64;
    gll16(g + (long)r0g * ldb + c0g, base);
    if constexpr (LB == 2) gll16(g + (long)r1g * ldb + c1g, base + 8192);
  };

  // T2: swizzled ds_read (matches source pre-swizzle)
  const u32 rx = (u32)((frow & 7) << 4);
  auto ldA = [&](int p, int i, int kk) -> bf16x8 {
    int row = wm * 128 + i * 16 + frow;
    u32 col = ((u32)(kk * 64 + fks * 16)) ^ rx;
    return *(const bf16x8*)(Ab + p * ABUF + row * 128 + col);
  };
  auto ldB = [&](int p, int j, int kk) -> bf16x8 {
    int row = wn * (BN / 4) + j * 16 + frow;
    u32 col = ((u32)(kk * 64 + fks * 16)) ^ rx;
    return *(const bf16x8*)(Bb + p * BBUF + row * 128 + col);
  };

  const f32x4 z4 = {0.f, 0.f, 0.f, 0.f};
  f32x4 acc[8][NF];
#pragma unroll
  for (int i = 0; i < 8; i++)
#pragma unroll
    for (int j = 0; j < NF; j++) acc[i][j] = z4;

  // prologue: tile0 fully + {A0,B0,B1}(1); A1(1) is issued at tile0-ph0
  stageA(0, 0); stageA(0, 1); stageB(0, 0); stageB(0, 1);
  if (NT > 1) {
    stageA(1, 0); stageB(1, 0); stageB(1, 1);
    vm_wait<VMN>();
  } else {
    vm_wait<0>();
  }
  wg_barrier();

  for (int t = 0; t < NT; ++t) {
    const int p = t & 1;
    bf16x8 a0[4][2], a1[4][2], b0[NQ][2], b1[NQ][2];
    // ---- phase 0: read A-mh0 (8) + B-nh0 (2*NQ); issue A1(t+1)
#pragma unroll
    for (int mi = 0; mi < 4; mi++)
#pragma unroll
      for (int kk = 0; kk < 2; kk++) a0[mi][kk] = ldA(p, mi, kk);
#pragma unroll
    for (int ni = 0; ni < NQ; ni++)
#pragma unroll
      for (int kk = 0; kk < 2; kk++) b0[ni][kk] = ldB(p, ni, kk);
    if (t + 1 < NT) stageA(t + 1, 1);
    wg_barrier();
    __builtin_amdgcn_s_setprio(1);
#pragma unroll
    for (int mi = 0; mi < 4; mi++)
#pragma unroll
      for (int ni = 0; ni < NQ; ni++)
#pragma unroll
        for (int kk = 0; kk < 2; kk++)
          acc[mi][ni] = __builtin_amdgcn_mfma_f32_16x16x32_bf16(a0[mi][kk], b0[ni][kk], acc[mi][ni], 0, 0, 0);
    __builtin_amdgcn_s_setprio(0);
    wg_barrier();
    // ---- phase 1: read B-nh1; no issue
#pragma unroll
    for (int ni = 0; ni < NQ; ni++)
#pragma unroll
      for (int kk = 0; kk < 2; kk++) b1[ni][kk] = ldB(p, NQ + ni, kk);
    wg_barrier();
    __builtin_amdgcn_s_setprio(1);
#pragma unroll
    for (int mi = 0; mi < 4; mi++)
#pragma unroll
      for (int ni = 0; ni < NQ; ni++)
#pragma unroll
        for (int kk = 0; kk < 2; kk++)
          acc[mi][NQ + ni] = __builtin_amdgcn_mfma_f32_16x16x32_bf16(a0[mi][kk], b1[ni][kk], acc[mi][NQ + ni], 0, 0, 0);
    __builtin_amdgcn_s_setprio(0);
    wg_barrier();
    // ---- phase 2: read A-mh1; issue B0(t+2)
#pragma unroll
    for (int mi = 0; mi < 4; mi++)
#pragma unroll
      for (int kk = 0; kk < 2; kk++) a1[mi][kk] = ldA(p, 4 + mi, kk);
    if (t + 2 < NT) stageB(t + 2, 0);
    wg_barrier();
    __builtin_amdgcn_s_setprio(1);
#pragma unroll
    for (int mi = 0; mi < 4; mi++)
#pragma unroll
      for (int ni = 0; ni < NQ; ni++)
#pragma unroll
        for (int kk = 0; kk < 2; kk++)
          acc[4 + mi][NQ + ni] = __builtin_amdgcn_mfma_f32_16x16x32_bf16(a1[mi][kk], b1[ni][kk], acc[4 + mi][NQ + ni], 0, 0, 0);
    __builtin_amdgcn_s_setprio(0);
    wg_barrier();
    // ---- phase 3: no reads; issue A0(t+2), B1(t+2)
    if (t + 2 < NT) { stageA(t + 2, 0); stageB(t + 2, 1); }
    wg_barrier();
    __builtin_amdgcn_s_setprio(1);
#pragma unroll
    for (int mi = 0; mi < 4; mi++)
#pragma unroll
      for (int ni = 0; ni < NQ; ni++)
#pragma unroll
        for (int kk = 0; kk < 2; kk++)
          acc[4 + mi][ni] = __builtin_amdgcn_mfma_f32_16x16x32_bf16(a1[mi][kk], b0[ni][kk], acc[4 + mi][ni], 0, 0, 0);
    __builtin_amdgcn_s_setprio(0);
    if (t + 2 < NT) vm_wait<VMN>(); else vm_wait<0>();
    wg_barrier();
  }

  // epilogue: direct C store (row=(lane>>4)*4+r, col=lane&15 per frag)
#pragma unroll
  for (int i = 0; i < 8; i++) {
    long row = bm0 + wm * 128 + i * 16 + fks * 4;
#pragma unroll
    for (int j = 0; j < NF; j++) {
      long col = bn0 + wn * (BN / 4) + j * 16 + frow;
#pragma unroll
      for (int r = 0; r < 4; r++) {
        if constexpr (OUT_BF16) ((u16*)Cv)[(row + r) * ldc + col] = f2bf(acc[i][j][r]);
        else                    ((float*)Cv)[(row + r) * ldc + col] = acc[i][j][r];
      }
    }
  }
}

// ===========================================================================
// Rope q (cols 0..2047, scaled by dh^-0.5) and k (cols 2048..2175) in place;
// also scatter v (cols 2176..2303) into vt[b][d][pos].
// ===========================================================================
__global__ __launch_bounds__(256) void rope_kernel(u16* __restrict__ fused, u16* __restrict__ vt) {
  const int row = blockIdx.x;
  const int b = row >> 11, pos = row & 2047;
  u16* fr = fused + (long)row * 18688;
  const int t = threadIdx.x;
  const float fpos = (float)pos;
  const float QS = 0.08838834764831845f;  // 128^-0.5
#pragma unroll
  for (int i = 0; i < 4; i++) {
    int p = t + i * 256;          // 0..1023: 16 heads x 64 pairs
    int hh = p >> 6, d = p & 63;
    float ang = fpos * expf((float)d * -0.14391157f);  // ln(10000)/64
    float sn, cs; sincosf(ang, &sn, &cs);
    int base = hh * 128 + d;
    float x1 = bf2f(fr[base]), x2 = bf2f(fr[base + 64]);
    fr[base]      = f2bf((x1 * cs - x2 * sn) * QS);
    fr[base + 64] = f2bf((x2 * cs + x1 * sn) * QS);
  }
  if (t < 64) {
    int d = t;
    float ang = fpos * expf((float)d * -0.14391157f);
    float sn, cs; sincosf(ang, &sn, &cs);
    float x1 = bf2f(fr[2048 + d]), x2 = bf2f(fr[2112 + d]);
    fr[2048 + d] = f2bf(x1 * cs - x2 * sn);
    fr[2112 + d] = f2bf(x2 * cs + x1 * sn);
  }
  if (t < 128) vt[((long)(b * 128 + t)) * 2048 + pos] = fr[2176 + t];
}

// ===========================================================================
// Causal MQA flash attention. Block = (qt, h, b), 128 q-rows, 4 waves x 32 rows.
// ===========================================================================
__global__ __launch_bounds__(256, 2) void attn_kernel(const u16* __restrict__ fused,
                                                      const u16* __restrict__ vt,
                                                      u16* __restrict__ act2) {
  __shared__ u16 Ks[128 * 128];   // [kv][d]  (also reused as P staging)
  __shared__ u16 Vts[128 * 128];  // [d][kv]
  const int qt = blockIdx.x, h = blockIdx.y, b = blockIdx.z;
  const int tid = threadIdx.x, wave = tid >> 6, lane = tid & 63;
  const int frow = lane & 15, fk4 = lane >> 4;
  const long qrow0 = (long)b * 2048 + qt * 128;

  bf16x8 qf[2][4];
#pragma unroll
  for (int m = 0; m < 2; m++)
#pragma unroll
    for (int kk = 0; kk < 4; kk++)
      qf[m][kk] = *(const bf16x8*)&fused[(qrow0 + wave * 32 + m * 16 + frow) * 18688 +
                                         h * 128 + kk * 32 + fk4 * 8];

  const f32x4 z4 = {0.f, 0.f, 0.f, 0.f};
  f32x4 Oacc[2][8];
#pragma unroll
  for (int m = 0; m < 2; m++)
#pragma unroll
    for (int d = 0; d < 8; d++) Oacc[m][d] = z4;
  float mrun[2][4], lrun[2][4];
#pragma unroll
  for (int m = 0; m < 2; m++)
#pragma unroll
    for (int r = 0; r < 4; r++) { mrun[m][r] = -1e30f; lrun[m][r] = 0.f; }

  for (int jt = 0; jt <= qt; ++jt) {
    __syncthreads();
    const long kb = (long)b * 2048 + jt * 128;
#pragma unroll
    for (int s8 = 0; s8 < 8; s8++) {
      int gb = (s8 * 4 + wave) * 64;
      int g = gb + lane;
      int kv = g >> 4, gc8 = (g & 15) * 8;
      gll16(&fused[(kb + kv) * 18688 + 2048 + gc8], &Ks[gb * 8]);
      gll16(&vt[((long)b * 128 + kv) * 2048 + jt * 128 + gc8], &Vts[gb * 8]);
    }
    __syncthreads();

    f32x4 sc[2][8];
#pragma unroll
    for (int m = 0; m < 2; m++)
#pragma unroll
      for (int n = 0; n < 8; n++) sc[m][n] = z4;
#pragma unroll
    for (int n = 0; n < 8; n++) {
#pragma unroll
      for (int kk = 0; kk < 4; kk++) {
        bf16x8 kf = *(const bf16x8*)&Ks[(n * 16 + frow) * 128 + kk * 32 + fk4 * 8];
        sc[0][n] = __builtin_amdgcn_mfma_f32_16x16x32_bf16(qf[0][kk], kf, sc[0][n], 0, 0, 0);
        sc[1][n] = __builtin_amdgcn_mfma_f32_16x16x32_bf16(qf[1][kk], kf, sc[1][n], 0, 0, 0);
      }
    }
    if (jt == qt) {
#pragma unroll
      for (int m = 0; m < 2; m++)
#pragma unroll
        for (int n = 0; n < 8; n++)
#pragma unroll
          for (int r = 0; r < 4; r++) {
            int qp = wave * 32 + m * 16 + fk4 * 4 + r;
            int kp = n * 16 + frow;
            if (kp > qp) sc[m][n][r] = -1e30f;
          }
    }
#pragma unroll
    for (int m = 0; m < 2; m++) {
#pragma unroll
      for (int r = 0; r < 4; r++) {
        float mx = -1e30f;
#pragma unroll
        for (int n = 0; n < 8; n++) mx = fmaxf(mx, sc[m][n][r]);
#pragma unroll
        for (int o = 1; o < 16; o <<= 1) mx = fmaxf(mx, __shfl_xor(mx, o, 64));
        float mnew = fmaxf(mrun[m][r], mx);
        float corr = __expf(mrun[m][r] - mnew);
        mrun[m][r] = mnew;
        float rsum = 0.f;
#pragma unroll
        for (int n = 0; n < 8; n++) {
          float ppp = __expf(sc[m][n][r] - mnew);
          sc[m][n][r] = ppp;
          rsum += ppp;
        }
#pragma unroll
        for (int o = 1; o < 16; o <<= 1) rsum += __shfl_xor(rsum, o, 64);
        lrun[m][r] = lrun[m][r] * corr + rsum;
#pragma unroll
        for (int d = 0; d < 8; d++) Oacc[m][d][r] *= corr;
      }
    }
    __syncthreads();
    u16* Pw = &Ks[wave * 4096];
#pragma unroll
    for (int m = 0; m < 2; m++)
#pragma unroll
      for (int n = 0; n < 8; n++)
#pragma unroll
        for (int r = 0; r < 4; r++)
          Pw[(m * 16 + fk4 * 4 + r) * 128 + n * 16 + frow] = f2bf(sc[m][n][r]);
#pragma unroll
    for (int kk = 0; kk < 4; kk++) {
      bf16x8 p0 = *(const bf16x8*)&Pw[(frow) * 128 + kk * 32 + fk4 * 8];
      bf16x8 p1 = *(const bf16x8*)&Pw[(16 + frow) * 128 + kk * 32 + fk4 * 8];
#pragma unroll
      for (int d = 0; d < 8; d++) {
        bf16x8 vf = *(const bf16x8*)&Vts[(d * 16 + frow) * 128 + kk * 32 + fk4 * 8];
        Oacc[0][d] = __builtin_amdgcn_mfma_f32_16x16x32_bf16(p0, vf, Oacc[0][d], 0, 0, 0);
        Oacc[1][d] = __builtin_amdgcn_mfma_f32_16x16x32_bf16(p1, vf, Oacc[1][d], 0, 0, 0);
      }
    }
  }
#pragma unroll
  for (int m = 0; m < 2; m++)
#pragma unroll
    for (int d = 0; d < 8; d++)
#pragma unroll
      for (int r = 0; r < 4; r++) {
        long row = qrow0 + wave * 32 + m * 16 + fk4 * 4 + r;
        act2[row * 10240 + h * 128 + d * 16 + frow] = f2bf(Oacc[m][d][r] / lrun[m][r]);
      }
}

// ===========================================================================
// SwiGLU: act2[:, 2048+j] = silu(fused[:,10496+j]) * fused[:,2304+j]
// ===========================================================================
__global__ __launch_bounds__(256) void swiglu_kernel(const u16* __restrict__ fused,
                                                     u16* __restrict__ act2) {
  long idx8 = ((long)blockIdx.x * 256 + threadIdx.x) * 8;
  int row = (int)(idx8 >> 13);
  int j = (int)(idx8 & 8191);
  const u16* fr = fused + (long)row * 18688;
  union { uint4 u; u16 h[8]; } xv, gv, ov;
  xv.u = *(const uint4*)&fr[2304 + j];
  gv.u = *(const uint4*)&fr[10496 + j];
#pragma unroll
  for (int i = 0; i < 8; i++) {
    float xf = bf2f(xv.h[i]);
    float gf = bf2f(gv.h[i]);
    float sg = gf / (1.f + __expf(-gf));
    ov.h[i] = f2bf(sg * xf);
  }
  *(uint4*)&act2[(long)row * 10240 + 2048 + j] = ov.u;
}

// ===========================================================================
extern "C" void kernel_launch(void* const* d_in, const int* in_sizes, int n_in,
                              void* d_out, int out_size, void* d_ws, size_t ws_size,
                              hipStream_t stream) {
  (void)in_sizes; (void)n_in; (void)out_size; (void)ws_size;
  const float* x          = (const float*)d_in[0];
  const float* gamma      = (const float*)d_in[1];
  const float* w_fused    = (const float*)d_in[2];
  const float* w_attn_out = (const float*)d_in[3];
  const float* w_ff_out   = (const float*)d_in[4];
  const float* qA = (const float*)d_in[5];
  const float* qB = (const float*)d_in[6];
  const float* kA = (const float*)d_in[7];
  const float* kB = (const float*)d_in[8];
  const float* vA = (const float*)d_in[9];
  const float* vB = (const float*)d_in[10];
  const float* oA = (const float*)d_in[11];
  const float* oB = (const float*)d_in[12];
  float* out = (float*)d_out;

  char* w = (char*)d_ws;
  auto alloc = [&](size_t bytes) { char* p = w; w += (bytes + 255) & ~(size_t)255; return p; };
  u16*   xn     = (u16*)alloc((size_t)4096 * 2048 * 2);
  u16*   wf_t   = (u16*)alloc((size_t)18688 * 2048 * 2);
  u16*   wcat_t = (u16*)alloc((size_t)2048 * 10240 * 2);
  u16*   fused  = (u16*)alloc((size_t)4096 * 18688 * 2);
  u16*   act2   = (u16*)alloc((size_t)4096 * 10240 * 2);
  u16*   vtb    = (u16*)alloc((size_t)2 * 128 * 2048 * 2);
  float* delta  = (float*)alloc((size_t)2048 * 2304 * 4);

  // allow >64KB dynamic LDS for the 8-phase GEMMs (host-side, idempotent)
  hipFuncSetAttribute((const void*)gemm8p<1, 256>, hipFuncAttributeMaxDynamicSharedMemorySize, 131072);
  hipFuncSetAttribute((const void*)gemm8p<0, 128>, hipFuncAttributeMaxDynamicSharedMemorySize, 98304);

  // 1) LayerNorm
  ln_kernel<<<4096, 256, 0, stream>>>(x, gamma, xn);

  // 2) LoRA deltas for q/k/v, fold+transpose w_fused -> wf_t (bf16)
  lora_mm<<<dim3(8, 2048), 256, 0, stream>>>(qA, qB, delta, 2048, 2304, 0);
  lora_mm<<<dim3(1, 2048), 256, 0, stream>>>(kA, kB, delta, 128, 2304, 2048);
  lora_mm<<<dim3(1, 2048), 256, 0, stream>>>(vA, vB, delta, 128, 2304, 2176);
  transpose_conv<<<dim3(584, 64), 256, 0, stream>>>(w_fused, 18688, delta, 2304, 2304,
                                                    wf_t, 2048, 0);

  // 3) fused GEMM: xn @ wf' -> fused (bf16). grid = 73*16 = 1168 (mult of 8)
  gemm8p<1, 256><<<1168, 512, 131072, stream>>>(xn, wf_t, fused, 2048, 2048, 2048, 18688, 16);

  // 4) rope q/k in place + build V^T
  rope_kernel<<<4096, 256, 0, stream>>>(fused, vtb);

  // 5) output weights: w_attn_out + oA@oB, w_ff_out -> wcat_t (transposed bf16)
  lora_mm<<<dim3(8, 2048), 256, 0, stream>>>(oA, oB, delta, 2048, 2048, 0);
  transpose_conv<<<dim3(64, 64), 256, 0, stream>>>(w_attn_out, 2048, delta, 2048, 2048,
                                                   wcat_t, 10240, 0);
  transpose_conv<<<dim3(64, 256), 256, 0, stream>>>(w_ff_out, 2048, (const float*)nullptr, 0, 0,
                                                    wcat_t, 10240, 2048);

  // 6) flash attention -> act2[:, 0:2048]
  attn_kernel<<<dim3(16, 16, 2), 256, 0, stream>>>(fused, vtb, act2);

  // 7) SwiGLU -> act2[:, 2048:10240]
  swiglu_kernel<<<16384, 256, 0, stream>>>(fused, act2);

  // 8) concat GEMM: [attn_out | ff] @ wcat' -> d_out (fp32). grid = 16*16 = 256
  gemm8p<0, 128><<<256, 512, 98304, stream>>>(act2, wcat_t, out, 10240, 10240, 10240, 2048, 16);
}

// Round 5
// 1020.275 us; speedup vs baseline: 1.2745x; 1.0557x over previous
//
#include <hip/hip_runtime.h>

typedef unsigned short u16;
typedef unsigned int   u32;
typedef __bf16  bf16x8 __attribute__((ext_vector_type(8)));
typedef float   f32x4  __attribute__((ext_vector_type(4)));

#define DEV __device__ __forceinline__

// ---------- scalar bf16 helpers (bit-level, RNE) ----------
DEV float bf2f(u16 b) { return __uint_as_float(((u32)b) << 16); }
DEV u16 f2bf(float f) {
  u32 u = __float_as_uint(f);
  u32 r = (u + 0x7fffu + ((u >> 16) & 1u)) >> 16;
  return (u16)r;
}

// ---------- async global->LDS, 16B per lane, dest = wave-uniform base + lane*16 ----------
DEV void gll16(const void* g, void* l) {
  __builtin_amdgcn_global_load_lds((const __attribute__((address_space(1))) void*)g,
                                   (__attribute__((address_space(3))) void*)l, 16, 0, 0);
}
DEV void sb0() { __builtin_amdgcn_sched_barrier(0); }
DEV void wg_barrier() { sb0(); __builtin_amdgcn_s_barrier(); sb0(); }
template <int N> DEV void vm_wait() {
  if constexpr (N == 6)      asm volatile("s_waitcnt vmcnt(6)" ::: "memory");
  else if constexpr (N == 4) asm volatile("s_waitcnt vmcnt(4)" ::: "memory");
  else                       asm volatile("s_waitcnt vmcnt(0)" ::: "memory");
}

// ===========================================================================
// LayerNorm: x fp32 [4096][2048] -> xn bf16. One block per row.
// ===========================================================================
__global__ __launch_bounds__(256) void ln_kernel(const float* __restrict__ x,
                                                 const float* __restrict__ gamma,
                                                 u16* __restrict__ xn) {
  __shared__ float red[4];
  const int row = blockIdx.x, t = threadIdx.x;
  const float* xr = x + (long)row * 2048;
  float4 v0 = ((const float4*)xr)[t * 2];
  float4 v1 = ((const float4*)xr)[t * 2 + 1];
  float s = (v0.x + v0.y) + (v0.z + v0.w) + (v1.x + v1.y) + (v1.z + v1.w);
#pragma unroll
  for (int o = 32; o >= 1; o >>= 1) s += __shfl_xor(s, o, 64);
  if ((t & 63) == 0) red[t >> 6] = s;
  __syncthreads();
  const float mu = (red[0] + red[1] + red[2] + red[3]) * (1.f / 2048.f);
  __syncthreads();
  float a0 = v0.x - mu, a1 = v0.y - mu, a2 = v0.z - mu, a3 = v0.w - mu;
  float a4 = v1.x - mu, a5 = v1.y - mu, a6 = v1.z - mu, a7 = v1.w - mu;
  float q = a0*a0 + a1*a1 + a2*a2 + a3*a3 + a4*a4 + a5*a5 + a6*a6 + a7*a7;
#pragma unroll
  for (int o = 32; o >= 1; o >>= 1) q += __shfl_xor(q, o, 64);
  if ((t & 63) == 0) red[t >> 6] = q;
  __syncthreads();
  const float var = (red[0] + red[1] + red[2] + red[3]) * (1.f / 2048.f);
  const float rs = rsqrtf(var + 1e-5f);
  float4 g0 = ((const float4*)gamma)[t * 2];
  float4 g1 = ((const float4*)gamma)[t * 2 + 1];
  union { uint4 u; u16 h[8]; } o;
  o.h[0] = f2bf(a0 * rs * g0.x); o.h[1] = f2bf(a1 * rs * g0.y);
  o.h[2] = f2bf(a2 * rs * g0.z); o.h[3] = f2bf(a3 * rs * g0.w);
  o.h[4] = f2bf(a4 * rs * g1.x); o.h[5] = f2bf(a5 * rs * g1.y);
  o.h[6] = f2bf(a6 * rs * g1.z); o.h[7] = f2bf(a7 * rs * g1.w);
  ((uint4*)(xn + (long)row * 2048))[t] = o.u;
}

// ===========================================================================
// LoRA rank-8 outer products: dst[k][doff+n] = sum_r A[k][r]*B[r][n]
// ===========================================================================
__global__ __launch_bounds__(256) void lora_mm(const float* __restrict__ A,
                                               const float* __restrict__ B,
                                               float* __restrict__ dst,
                                               int ncols, int dstride, int doff) {
  int n = blockIdx.x * 256 + threadIdx.x;
  int k = blockIdx.y;
  if (n >= ncols) return;
  float acc = 0.f;
#pragma unroll
  for (int r = 0; r < 8; r++) acc += A[k * 8 + r] * B[r * ncols + n];
  dst[(long)k * dstride + doff + n] = acc;
}

// ===========================================================================
// Transpose + (optional) delta add + convert fp32 -> bf16.
// ===========================================================================
__global__ __launch_bounds__(256) void transpose_conv(const float* __restrict__ src, int sstride,
                                                      const float* __restrict__ delta, int dstride, int dcols,
                                                      u16* __restrict__ dst, int dst_stride, int dst_off) {
  __shared__ float tile[32][33];
  const int c0 = blockIdx.x * 32, r0 = blockIdx.y * 32;
  const int tx = threadIdx.x & 31, ty = threadIdx.x >> 5;
  const bool hasd = (delta != nullptr) && (c0 < dcols);
#pragma unroll
  for (int i = 0; i < 4; i++) {
    int r = r0 + ty + i * 8;
    float v = src[(long)r * sstride + c0 + tx];
    if (hasd) v += delta[(long)r * dstride + c0 + tx];
    tile[ty + i * 8][tx] = v;
  }
  __syncthreads();
#pragma unroll
  for (int i = 0; i < 4; i++) {
    int n = c0 + ty + i * 8;
    dst[(long)n * dst_stride + dst_off + r0 + tx] = f2bf(tile[tx][ty + i * 8]);
  }
}

// ===========================================================================
// 8-phase 256xBN bf16 GEMM (T1..T5), K-loop unrolled x2 with LITERAL parity.
// C[M][N] = A[M][K] @ Bt[N][K]^T.  8 waves (2Mx4N), BK=64, dbuf LDS,
// XOR-swizzle both sides, counted vmcnt, setprio.  K is a template param so
// NT is constexpr and all LDS offsets fold to immediates.
// ===========================================================================
template <int OUT_BF16, int BN, int K>
__global__ __launch_bounds__(512, 1) void gemm8p(const u16* __restrict__ A,
                                                 const u16* __restrict__ Bt,
                                                 void* __restrict__ Cv,
                                                 int lda, int ldb, int ldc, int ntm) {
  extern __shared__ char lds[];
  constexpr int LB   = (BN == 256) ? 2 : 1;
  constexpr int NF   = BN / 64;
  constexpr int NQ   = NF / 2;
  constexpr int ABUF = 256 * 64 * 2;
  constexpr int BBUF = BN * 64 * 2;
  constexpr int VMN  = 2 + 2 * LB;
  constexpr int NT   = K / 64;

  const int tid = threadIdx.x, wave = tid >> 6, lane = tid & 63;
  const int wm = wave >> 2, wn = wave & 3;
  const int frow = lane & 15, fks = lane >> 4;

  // T1: XCD-aware bijective swizzle (grid % 8 == 0 at both call sites)
  const int nwg = gridDim.x, orig = blockIdx.x;
  const int swz = (orig & 7) * (nwg >> 3) + (orig >> 3);
  const int tm = swz % ntm, tn = swz / ntm;
  const long bm0 = (long)tm * 256, bn0 = (long)tn * BN;

  char* Ab = lds;
  char* Bb = lds + 2 * ABUF;

  // staging geometry: granule G -> row G>>3, col granule (G&7)^((G>>3)&7)
  const int G0 = wave * 64 + lane;
  const int r0g = G0 >> 3, c0g = ((G0 & 7) ^ (r0g & 7)) * 8;
  const int G1 = 512 + G0;
  const int r1g = G1 >> 3, c1g = ((G1 & 7) ^ (r1g & 7)) * 8;

  // hoisted per-lane stage source pointers
  const u16* pA00 = A + (bm0 + r0g) * (long)lda + c0g;
  const u16* pA01 = A + (bm0 + r1g) * (long)lda + c1g;
  const u16* pA10 = A + (bm0 + 128 + r0g) * (long)lda + c0g;
  const u16* pA11 = A + (bm0 + 128 + r1g) * (long)lda + c1g;
  const u16* pB00 = Bt + (bn0 + r0g) * (long)ldb + c0g;
  const u16* pB01 = (LB == 2) ? Bt + (bn0 + r1g) * (long)ldb + c1g : nullptr;
  const u16* pB10 = Bt + (bn0 + BN / 2 + r0g) * (long)ldb + c0g;
  const u16* pB11 = (LB == 2) ? Bt + (bn0 + BN / 2 + r1g) * (long)ldb + c1g : nullptr;

  auto stA = [&](int kt, int X, int par) {
    char* base = Ab + par * ABUF + X * 16384 + wave * 1024;
    gll16((X ? pA10 : pA00) + (long)kt * 64, base);
    gll16((X ? pA11 : pA01) + (long)kt * 64, base + 8192);
  };
  auto stB = [&](int kt, int X, int par) {
    char* base = Bb + par * BBUF + X * (BBUF / 2) + wave * 1024;
    gll16((X ? pB10 : pB00) + (long)kt * 64, base);
    if constexpr (LB == 2) gll16((X ? pB11 : pB01) + (long)kt * 64, base + 8192);
  };

  // hoisted swizzled ds_read bases
  const int aRow = wm * 128 + frow;
  const int bRow = wn * (BN / 4) + frow;
  const u32 rx = (u32)((frow & 7) << 4);
  const u32 colk0 = ((u32)(fks * 16)) ^ rx;
  const u32 colk1 = ((u32)(64 + fks * 16)) ^ rx;

#define LDA8(P, i, kk) (*(const bf16x8*)(Ab + (P) * ABUF + (aRow + (i) * 16) * 128 + ((kk) ? colk1 : colk0)))
#define LDB8(P, j, kk) (*(const bf16x8*)(Bb + (P) * BBUF + (bRow + (j) * 16) * 128 + ((kk) ? colk1 : colk0)))

  const f32x4 z4 = {0.f, 0.f, 0.f, 0.f};
  f32x4 acc[8][NF];
#pragma unroll
  for (int i = 0; i < 8; i++)
#pragma unroll
    for (int j = 0; j < NF; j++) acc[i][j] = z4;

#define CL(AH, AF, BF, NO)                                                              \
  __builtin_amdgcn_s_setprio(1);                                                        \
  _Pragma("unroll") for (int mi = 0; mi < 4; mi++)                                      \
    _Pragma("unroll") for (int ni = 0; ni < NQ; ni++)                                   \
      _Pragma("unroll") for (int kk = 0; kk < 2; kk++)                                  \
        acc[(AH) + mi][(NO) + ni] = __builtin_amdgcn_mfma_f32_16x16x32_bf16(            \
            AF[mi][kk], BF[ni][kk], acc[(AH) + mi][(NO) + ni], 0, 0, 0);                \
  __builtin_amdgcn_s_setprio(0);

#define GTILE(T, P, DS1, DS2, LW) {                                                     \
  const int t_ = (T);                                                                   \
  bf16x8 a0[4][2], a1[4][2], b0r[NQ][2], b1r[NQ][2];                                    \
  _Pragma("unroll") for (int mi = 0; mi < 4; mi++) {                                    \
    a0[mi][0] = LDA8(P, mi, 0); a0[mi][1] = LDA8(P, mi, 1); }                           \
  _Pragma("unroll") for (int ni = 0; ni < NQ; ni++) {                                   \
    b0r[ni][0] = LDB8(P, ni, 0); b0r[ni][1] = LDB8(P, ni, 1); }                         \
  if (DS1) stA(t_ + 1, 1, (P) ^ 1);                                                     \
  wg_barrier();                                                                         \
  CL(0, a0, b0r, 0)                                                                     \
  wg_barrier();                                                                         \
  _Pragma("unroll") for (int ni = 0; ni < NQ; ni++) {                                   \
    b1r[ni][0] = LDB8(P, NQ + ni, 0); b1r[ni][1] = LDB8(P, NQ + ni, 1); }               \
  wg_barrier();                                                                         \
  CL(0, a0, b1r, NQ)                                                                    \
  wg_barrier();                                                                         \
  _Pragma("unroll") for (int mi = 0; mi < 4; mi++) {                                    \
    a1[mi][0] = LDA8(P, 4 + mi, 0); a1[mi][1] = LDA8(P, 4 + mi, 1); }                   \
  if (DS2) stB(t_ + 2, 0, P);                                                           \
  wg_barrier();                                                                         \
  CL(4, a1, b1r, NQ)                                                                    \
  wg_barrier();                                                                         \
  if (DS2) { stA(t_ + 2, 0, P); stB(t_ + 2, 1, P); }                                    \
  wg_barrier();                                                                         \
  CL(4, a1, b0r, 0)                                                                     \
  if ((LW) == 0) vm_wait<VMN>(); else if ((LW) == 1) vm_wait<0>();                      \
  if ((LW) != 2) wg_barrier();                                                          \
}

  // prologue: tile0 fully + {A0,B0,B1}(1); A1(1) issued at tile0-ph0
  stA(0, 0, 0); stA(0, 1, 0); stB(0, 0, 0); stB(0, 1, 0);
  stA(1, 0, 1); stB(1, 0, 1); stB(1, 1, 1);
  vm_wait<VMN>();
  wg_barrier();

  for (int tt = 0; tt + 3 < NT; tt += 2) {
    GTILE(tt,     0, 1, 1, 0)
    GTILE(tt + 1, 1, 1, 1, 0)
  }
  GTILE(NT - 2, 0, 1, 0, 1)
  GTILE(NT - 1, 1, 0, 0, 2)

#undef GTILE
#undef CL
#undef LDA8
#undef LDB8

  // epilogue: C row = (lane>>4)*4 + r, col = lane&15 per frag
#pragma unroll
  for (int i = 0; i < 8; i++) {
    long row = bm0 + wm * 128 + i * 16 + fks * 4;
#pragma unroll
    for (int j = 0; j < NF; j++) {
      long col = bn0 + wn * (BN / 4) + j * 16 + frow;
#pragma unroll
      for (int r = 0; r < 4; r++) {
        if constexpr (OUT_BF16) ((u16*)Cv)[(row + r) * ldc + col] = f2bf(acc[i][j][r]);
        else                    ((float*)Cv)[(row + r) * ldc + col] = acc[i][j][r];
      }
    }
  }
}

// ===========================================================================
// Rope q (scaled) + k in place, scatter v into vt[b][d][pos].
// sin/cos via 64-entry LDS table (17x fewer transcendentals).
// ===========================================================================
__global__ __launch_bounds__(256) void rope_kernel(u16* __restrict__ fused, u16* __restrict__ vt) {
  __shared__ float sn_t[64], cs_t[64];
  const int row = blockIdx.x;
  const int b = row >> 11, pos = row & 2047;
  u16* fr = fused + (long)row * 18688;
  const int t = threadIdx.x;
  if (t < 64) {
    float ang = (float)pos * expf((float)t * -0.14391157f);  // ln(10000)/64
    sincosf(ang, &sn_t[t], &cs_t[t]);
  }
  __syncthreads();
  const float QS = 0.08838834764831845f;  // 128^-0.5
#pragma unroll
  for (int i = 0; i < 4; i++) {
    int p = t + i * 256;          // 0..1023: 16 heads x 64 pairs
    int hh = p >> 6, d = p & 63;
    float sn = sn_t[d], cs = cs_t[d];
    int base = hh * 128 + d;
    float x1 = bf2f(fr[base]), x2 = bf2f(fr[base + 64]);
    fr[base]      = f2bf((x1 * cs - x2 * sn) * QS);
    fr[base + 64] = f2bf((x2 * cs + x1 * sn) * QS);
  }
  if (t < 64) {
    float sn = sn_t[t], cs = cs_t[t];
    float x1 = bf2f(fr[2048 + t]), x2 = bf2f(fr[2112 + t]);
    fr[2048 + t] = f2bf(x1 * cs - x2 * sn);
    fr[2112 + t] = f2bf(x2 * cs + x1 * sn);
  }
  if (t < 128) vt[((long)(b * 128 + t)) * 2048 + pos] = fr[2176 + t];
}

// ===========================================================================
// Causal MQA flash attention. Block = (qt, h, b), 128 q-rows, 4 waves x 32 rows.
// K/V/P LDS tiles XOR-swizzled at 16B-granule level (pre-swizzled global
// source for the gll16 tiles; swizzled write+read for P).
// ===========================================================================
__global__ __launch_bounds__(256, 2) void attn_kernel(const u16* __restrict__ fused,
                                                      const u16* __restrict__ vt,
                                                      u16* __restrict__ act2) {
  __shared__ u16 Ks[128 * 128];   // [kv][d]  (reused as P staging)
  __shared__ u16 Vts[128 * 128];  // [d][kv]
  const int qt = blockIdx.x, h = blockIdx.y, b = blockIdx.z;
  const int tid = threadIdx.x, wave = tid >> 6, lane = tid & 63;
  const int frow = lane & 15, fk4 = lane >> 4, fr7 = frow & 7;
  const long qrow0 = (long)b * 2048 + qt * 128;

  // hoisted staging source pointers (pre-swizzled col granule)
  const int kvb = (wave * 64 + lane) >> 4;             // 0..15
  const int gsw = ((lane & 15) ^ (kvb & 7)) * 8;       // swizzled col elem
  const u16* pKsrc = fused + ((long)b * 2048 + kvb) * 18688 + 2048 + gsw;
  const u16* pVsrc = vt + ((long)b * 128 + kvb) * 2048 + gsw;

  bf16x8 qf[2][4];
#pragma unroll
  for (int m = 0; m < 2; m++)
#pragma unroll
    for (int kk = 0; kk < 4; kk++)
      qf[m][kk] = *(const bf16x8*)&fused[(qrow0 + wave * 32 + m * 16 + frow) * 18688 +
                                         h * 128 + kk * 32 + fk4 * 8];

  const f32x4 z4 = {0.f, 0.f, 0.f, 0.f};
  f32x4 Oacc[2][8];
#pragma unroll
  for (int m = 0; m < 2; m++)
#pragma unroll
    for (int d = 0; d < 8; d++) Oacc[m][d] = z4;
  float mrun[2][4], lrun[2][4];
#pragma unroll
  for (int m = 0; m < 2; m++)
#pragma unroll
    for (int r = 0; r < 4; r++) { mrun[m][r] = -1e30f; lrun[m][r] = 0.f; }

  for (int jt = 0; jt <= qt; ++jt) {
    __syncthreads();
#pragma unroll
    for (int s8 = 0; s8 < 8; s8++) {
      int gb = (s8 * 4 + wave) * 64;
      gll16(pKsrc + ((long)jt * 128 + s8 * 16) * 18688, &Ks[gb * 8]);
      gll16(pVsrc + jt * 128 + (long)s8 * 16 * 2048, &Vts[gb * 8]);
    }
    __syncthreads();

    f32x4 sc[2][8];
#pragma unroll
    for (int m = 0; m < 2; m++)
#pragma unroll
      for (int n = 0; n < 8; n++) sc[m][n] = z4;
#pragma unroll
    for (int n = 0; n < 8; n++) {
#pragma unroll
      for (int kk = 0; kk < 4; kk++) {
        bf16x8 kf = *(const bf16x8*)&Ks[(n * 16 + frow) * 128 + ((kk * 4 + fk4) ^ fr7) * 8];
        sc[0][n] = __builtin_amdgcn_mfma_f32_16x16x32_bf16(qf[0][kk], kf, sc[0][n], 0, 0, 0);
        sc[1][n] = __builtin_amdgcn_mfma_f32_16x16x32_bf16(qf[1][kk], kf, sc[1][n], 0, 0, 0);
      }
    }
    if (jt == qt) {
#pragma unroll
      for (int m = 0; m < 2; m++)
#pragma unroll
        for (int n = 0; n < 8; n++)
#pragma unroll
          for (int r = 0; r < 4; r++) {
            int qp = wave * 32 + m * 16 + fk4 * 4 + r;
            int kp = n * 16 + frow;
            if (kp > qp) sc[m][n][r] = -1e30f;
          }
    }
#pragma unroll
    for (int m = 0; m < 2; m++) {
#pragma unroll
      for (int r = 0; r < 4; r++) {
        float mx = -1e30f;
#pragma unroll
        for (int n = 0; n < 8; n++) mx = fmaxf(mx, sc[m][n][r]);
#pragma unroll
        for (int o = 1; o < 16; o <<= 1) mx = fmaxf(mx, __shfl_xor(mx, o, 64));
        float mnew = fmaxf(mrun[m][r], mx);
        float corr = __expf(mrun[m][r] - mnew);
        mrun[m][r] = mnew;
        float rsum = 0.f;
#pragma unroll
        for (int n = 0; n < 8; n++) {
          float ppp = __expf(sc[m][n][r] - mnew);
          sc[m][n][r] = ppp;
          rsum += ppp;
        }
#pragma unroll
        for (int o = 1; o < 16; o <<= 1) rsum += __shfl_xor(rsum, o, 64);
        lrun[m][r] = lrun[m][r] * corr + rsum;
#pragma unroll
        for (int d = 0; d < 8; d++) Oacc[m][d][r] *= corr;
      }
    }
    __syncthreads();
    u16* Pw = &Ks[wave * 4096];
#pragma unroll
    for (int m = 0; m < 2; m++)
#pragma unroll
      for (int n = 0; n < 8; n++)
#pragma unroll
        for (int r = 0; r < 4; r++) {
          int prow = m * 16 + fk4 * 4 + r;
          Pw[prow * 128 + ((n * 2 + (frow >> 3)) ^ (prow & 7)) * 8 + fr7] = f2bf(sc[m][n][r]);
        }
#pragma unroll
    for (int kk = 0; kk < 4; kk++) {
      bf16x8 p0 = *(const bf16x8*)&Pw[frow * 128 + ((kk * 4 + fk4) ^ fr7) * 8];
      bf16x8 p1 = *(const bf16x8*)&Pw[(16 + frow) * 128 + ((kk * 4 + fk4) ^ fr7) * 8];
#pragma unroll
      for (int d = 0; d < 8; d++) {
        bf16x8 vf = *(const bf16x8*)&Vts[(d * 16 + frow) * 128 + ((kk * 4 + fk4) ^ fr7) * 8];
        Oacc[0][d] = __builtin_amdgcn_mfma_f32_16x16x32_bf16(p0, vf, Oacc[0][d], 0, 0, 0);
        Oacc[1][d] = __builtin_amdgcn_mfma_f32_16x16x32_bf16(p1, vf, Oacc[1][d], 0, 0, 0);
      }
    }
  }
#pragma unroll
  for (int m = 0; m < 2; m++)
#pragma unroll
    for (int d = 0; d < 8; d++)
#pragma unroll
      for (int r = 0; r < 4; r++) {
        long row = qrow0 + wave * 32 + m * 16 + fk4 * 4 + r;
        act2[row * 10240 + h * 128 + d * 16 + frow] = f2bf(Oacc[m][d][r] / lrun[m][r]);
      }
}

// ===========================================================================
// SwiGLU: act2[:, 2048+j] = silu(fused[:,10496+j]) * fused[:,2304+j]
// ===========================================================================
__global__ __launch_bounds__(256) void swiglu_kernel(const u16* __restrict__ fused,
                                                     u16* __restrict__ act2) {
  long idx8 = ((long)blockIdx.x * 256 + threadIdx.x) * 8;
  int row = (int)(idx8 >> 13);
  int j = (int)(idx8 & 8191);
  const u16* fr = fused + (long)row * 18688;
  union { uint4 u; u16 h[8]; } xv, gv, ov;
  xv.u = *(const uint4*)&fr[2304 + j];
  gv.u = *(const uint4*)&fr[10496 + j];
#pragma unroll
  for (int i = 0; i < 8; i++) {
    float xf = bf2f(xv.h[i]);
    float gf = bf2f(gv.h[i]);
    float sg = gf / (1.f + __expf(-gf));
    ov.h[i] = f2bf(sg * xf);
  }
  *(uint4*)&act2[(long)row * 10240 + 2048 + j] = ov.u;
}

// ===========================================================================
extern "C" void kernel_launch(void* const* d_in, const int* in_sizes, int n_in,
                              void* d_out, int out_size, void* d_ws, size_t ws_size,
                              hipStream_t stream) {
  (void)in_sizes; (void)n_in; (void)out_size; (void)ws_size;
  const float* x          = (const float*)d_in[0];
  const float* gamma      = (const float*)d_in[1];
  const float* w_fused    = (const float*)d_in[2];
  const float* w_attn_out = (const float*)d_in[3];
  const float* w_ff_out   = (const float*)d_in[4];
  const float* qA = (const float*)d_in[5];
  const float* qB = (const float*)d_in[6];
  const float* kA = (const float*)d_in[7];
  const float* kB = (const float*)d_in[8];
  const float* vA = (const float*)d_in[9];
  const float* vB = (const float*)d_in[10];
  const float* oA = (const float*)d_in[11];
  const float* oB = (const float*)d_in[12];
  float* out = (float*)d_out;

  char* w = (char*)d_ws;
  auto alloc = [&](size_t bytes) { char* p = w; w += (bytes + 255) & ~(size_t)255; return p; };
  u16*   xn     = (u16*)alloc((size_t)4096 * 2048 * 2);
  u16*   wf_t   = (u16*)alloc((size_t)18688 * 2048 * 2);
  u16*   wcat_t = (u16*)alloc((size_t)2048 * 10240 * 2);
  u16*   fused  = (u16*)alloc((size_t)4096 * 18688 * 2);
  u16*   act2   = (u16*)alloc((size_t)4096 * 10240 * 2);
  u16*   vtb    = (u16*)alloc((size_t)2 * 128 * 2048 * 2);
  float* delta  = (float*)alloc((size_t)2048 * 2304 * 4);

  hipFuncSetAttribute((const void*)gemm8p<1, 256, 2048>, hipFuncAttributeMaxDynamicSharedMemorySize, 131072);
  hipFuncSetAttribute((const void*)gemm8p<0, 128, 10240>, hipFuncAttributeMaxDynamicSharedMemorySize, 98304);

  // 1) LayerNorm
  ln_kernel<<<4096, 256, 0, stream>>>(x, gamma, xn);

  // 2) LoRA deltas for q/k/v, fold+transpose w_fused -> wf_t (bf16)
  lora_mm<<<dim3(8, 2048), 256, 0, stream>>>(qA, qB, delta, 2048, 2304, 0);
  lora_mm<<<dim3(1, 2048), 256, 0, stream>>>(kA, kB, delta, 128, 2304, 2048);
  lora_mm<<<dim3(1, 2048), 256, 0, stream>>>(vA, vB, delta, 128, 2304, 2176);
  transpose_conv<<<dim3(584, 64), 256, 0, stream>>>(w_fused, 18688, delta, 2304, 2304,
                                                    wf_t, 2048, 0);

  // 3) fused GEMM: xn @ wf' -> fused (bf16). grid = 73*16 = 1168
  gemm8p<1, 256, 2048><<<1168, 512, 131072, stream>>>(xn, wf_t, fused, 2048, 2048, 18688, 16);

  // 4) rope q/k in place + build V^T
  rope_kernel<<<4096, 256, 0, stream>>>(fused, vtb);

  // 5) output weights: w_attn_out + oA@oB, w_ff_out -> wcat_t (transposed bf16)
  lora_mm<<<dim3(8, 2048), 256, 0, stream>>>(oA, oB, delta, 2048, 2048, 0);
  transpose_conv<<<dim3(64, 64), 256, 0, stream>>>(w_attn_out, 2048, delta, 2048, 2048,
                                                   wcat_t, 10240, 0);
  transpose_conv<<<dim3(64, 256), 256, 0, stream>>>(w_ff_out, 2048, (const float*)nullptr, 0, 0,
                                                    wcat_t, 10240, 2048);

  // 6) flash attention -> act2[:, 0:2048]
  attn_kernel<<<dim3(16, 16, 2), 256, 0, stream>>>(fused, vtb, act2);

  // 7) SwiGLU -> act2[:, 2048:10240]
  swiglu_kernel<<<16384, 256, 0, stream>>>(fused, act2);

  // 8) concat GEMM: [attn_out | ff] @ wcat' -> d_out (fp32). grid = 16*16 = 256
  gemm8p<0, 128, 10240><<<256, 512, 98304, stream>>>(act2, wcat_t, out, 10240, 10240, 2048, 16);
}